// Round 7
// baseline (348.673 us; speedup 1.0000x reference)
//
#include <hip/hip_runtime.h>
#include <hip/hip_bf16.h>

#define LOG2E 1.44269504088896340736f

// =============================================================================
// MEASUREMENT ROUND: each kernel body wrapped in a runtime `reps` loop
// (proj x8, attn x8, oproj x24) so each dispatch exceeds the ~40us fill cutoff
// and shows up in rocprof's top-5 with its own counters. Math is idempotent and
// bit-identical per rep; `asm volatile("":::"memory")` defeats cross-rep CSE;
// trailing __syncthreads() prevents inter-rep LDS races.
// Next round restores reps=1 and targets the measured bottleneck.
// =============================================================================

__device__ __forceinline__ float fast_exp2(float x) {
#if __has_builtin(__builtin_amdgcn_exp2f)
    return __builtin_amdgcn_exp2f(x);
#else
    return exp2f(x);
#endif
}

// ---------------------------------------------------------------------------
// Stage 1: fused QKV projection with transposed outputs.
// ---------------------------------------------------------------------------
__global__ __launch_bounds__(256) void proj_kernel(
    const float* __restrict__ x, const float* __restrict__ emb,
    const float* __restrict__ Wq, const float* __restrict__ Wk,
    const float* __restrict__ Wv,
    float* __restrict__ qT, float* __restrict__ kT, float* __restrict__ vT,
    int reps)
{
    __shared__ __align__(16) float sx[4096];    // 8 rows x 512
    __shared__ __align__(16) float sred[4096];  // partial-sum reduction buffer
    const int t   = threadIdx.x;
    const int bid = blockIdx.x;
    const bool isQ = (bid < 256);
    const int rb  = isQ ? bid : (bid - 256);
    const int b  = rb >> 7;          // rows rb*8 -> batch
    const int q0 = (rb << 3) & 1023; // seq offset
    const float* src = (isQ ? x : emb) + (size_t)rb * 8 * 512;

    for (int rep = 0; rep < reps; ++rep) {
        #pragma unroll
        for (int i = 0; i < 16; ++i) sx[i * 256 + t] = src[i * 256 + t];
        __syncthreads();

        if (isQ) {
            const int cp = (t & 31) * 2;
            const int g  = t >> 5;
            const int d0 = g * 64;
            float acc0[8], acc1[8];
            #pragma unroll
            for (int r = 0; r < 8; ++r) { acc0[r] = 0.f; acc1[r] = 0.f; }
            for (int dd = 0; dd < 64; dd += 4) {
                const int d = d0 + dd;
                float2 w0 = *(const float2*)&Wq[(d + 0) * 64 + cp];
                float2 w1 = *(const float2*)&Wq[(d + 1) * 64 + cp];
                float2 w2 = *(const float2*)&Wq[(d + 2) * 64 + cp];
                float2 w3 = *(const float2*)&Wq[(d + 3) * 64 + cp];
                #pragma unroll
                for (int r = 0; r < 8; ++r) {
                    float4 xv = *(const float4*)&sx[r * 512 + d];
                    acc0[r] = fmaf(xv.x, w0.x, acc0[r]); acc1[r] = fmaf(xv.x, w0.y, acc1[r]);
                    acc0[r] = fmaf(xv.y, w1.x, acc0[r]); acc1[r] = fmaf(xv.y, w1.y, acc1[r]);
                    acc0[r] = fmaf(xv.z, w2.x, acc0[r]); acc1[r] = fmaf(xv.z, w2.y, acc1[r]);
                    acc0[r] = fmaf(xv.w, w3.x, acc0[r]); acc1[r] = fmaf(xv.w, w3.y, acc1[r]);
                }
            }
            #pragma unroll
            for (int r = 0; r < 8; ++r)
                *(float2*)&sred[g * 512 + r * 64 + cp] = make_float2(acc0[r], acc1[r]);
            __syncthreads();
            #pragma unroll
            for (int p = 0; p < 2; ++p) {
                int idx = p * 256 + t;
                int r = idx >> 6, h = idx & 63;
                float s = 0.f;
                #pragma unroll
                for (int g2 = 0; g2 < 8; ++g2) s += sred[g2 * 512 + r * 64 + h];
                qT[(size_t)(b * 64 + h) * 1024 + q0 + r] = s;
            }
        } else {
            const int cp = (t & 63) * 2;
            const int g  = t >> 6;
            const int d0 = g * 128;
            const float* Wsel = (cp < 64) ? (Wk + cp) : (Wv + (cp - 64));
            float acc0[8], acc1[8];
            #pragma unroll
            for (int r = 0; r < 8; ++r) { acc0[r] = 0.f; acc1[r] = 0.f; }
            for (int dd = 0; dd < 128; dd += 4) {
                const int d = d0 + dd;
                float2 w0 = *(const float2*)&Wsel[(d + 0) * 64];
                float2 w1 = *(const float2*)&Wsel[(d + 1) * 64];
                float2 w2 = *(const float2*)&Wsel[(d + 2) * 64];
                float2 w3 = *(const float2*)&Wsel[(d + 3) * 64];
                #pragma unroll
                for (int r = 0; r < 8; ++r) {
                    float4 xv = *(const float4*)&sx[r * 512 + d];
                    acc0[r] = fmaf(xv.x, w0.x, acc0[r]); acc1[r] = fmaf(xv.x, w0.y, acc1[r]);
                    acc0[r] = fmaf(xv.y, w1.x, acc0[r]); acc1[r] = fmaf(xv.y, w1.y, acc1[r]);
                    acc0[r] = fmaf(xv.z, w2.x, acc0[r]); acc1[r] = fmaf(xv.z, w2.y, acc1[r]);
                    acc0[r] = fmaf(xv.w, w3.x, acc0[r]); acc1[r] = fmaf(xv.w, w3.y, acc1[r]);
                }
            }
            #pragma unroll
            for (int r = 0; r < 8; ++r)
                *(float2*)&sred[g * 1024 + r * 128 + cp] = make_float2(acc0[r], acc1[r]);
            __syncthreads();
            #pragma unroll
            for (int p = 0; p < 4; ++p) {
                int idx = p * 256 + t;
                int r = idx >> 7, c = idx & 127;
                float s = 0.f;
                #pragma unroll
                for (int g2 = 0; g2 < 4; ++g2) s += sred[g2 * 1024 + r * 128 + c];
                if (c < 64) kT[(size_t)(b * 64 + c) * 1024 + q0 + r] = s;
                else        vT[(size_t)(b * 64 + (c - 64)) * 1024 + q0 + r] = s;
            }
        }
        __syncthreads();                       // no inter-rep LDS race
        asm volatile("" ::: "memory");         // defeat cross-rep CSE
    }
}

// ---------------------------------------------------------------------------
// Stage 2: attention (round-6 structure: qpt=2, j-split, partial num/den).
// ---------------------------------------------------------------------------
__global__ __launch_bounds__(256) void attn_kernel(
    const float* __restrict__ qT, const float* __restrict__ kT,
    const float* __restrict__ vT, float* __restrict__ numP,
    float* __restrict__ denP, int reps)
{
    __shared__ __align__(16) float kc[512];
    __shared__ __align__(16) float vc[512];
    __shared__ float wred[8];
    const int t   = threadIdx.x;
    const int bid = blockIdx.x;
    const int b   = bid >> 8;
    const int h   = (bid >> 2) & 63;
    const int qh  = (bid >> 1) & 1;    // q-half: rows qh*512 .. +511
    const int jh  = bid & 1;           // j-half: cols jh*512 .. +511
    const size_t base = (size_t)(b * 64 + h) * 1024;

    for (int rep = 0; rep < reps; ++rep) {
        // full-range k max/min (4 coalesced reads); stage only our j-slice
        float kmx = -1e30f, kmn = 1e30f;
        #pragma unroll
        for (int i = 0; i < 4; ++i) {
            float kv = kT[base + i * 256 + t];
            kmx = fmaxf(kmx, kv);
            kmn = fminf(kmn, kv);
            if ((i >> 1) == jh) kc[(i & 1) * 256 + t] = kv;
        }
        #pragma unroll
        for (int i2 = 0; i2 < 2; ++i2)
            vc[i2 * 256 + t] = vT[base + (jh * 2 + i2) * 256 + t];
        #pragma unroll
        for (int off = 32; off >= 1; off >>= 1) {
            kmx = fmaxf(kmx, __shfl_xor(kmx, off));
            kmn = fminf(kmn, __shfl_xor(kmn, off));
        }
        const int wid = t >> 6;
        if ((t & 63) == 0) { wred[wid] = kmx; wred[4 + wid] = kmn; }
        __syncthreads();
        kmx = fmaxf(fmaxf(wred[0], wred[1]), fmaxf(wred[2], wred[3]));
        kmn = fminf(fminf(wred[4], wred[5]), fminf(wred[6], wred[7]));

        const int qa = qh * 512 + t;
        const int qb = qa + 256;
        const float qsa = qT[base + qa];
        const float qsb = qT[base + qb];
        const float ma  = (qsa >= 0.f) ? qsa * kmx : qsa * kmn;
        const float mb  = (qsb >= 0.f) ? qsb * kmx : qsb * kmn;
        const float aa  = qsa * LOG2E;
        const float ab  = qsb * LOG2E;
        const float ba  = -ma * LOG2E;
        const float bb  = -mb * LOG2E;

        float da0 = 0.f, da1 = 0.f, da2 = 0.f, da3 = 0.f;
        float na0 = 0.f, na1 = 0.f, na2 = 0.f, na3 = 0.f;
        float db0 = 0.f, db1 = 0.f, db2 = 0.f, db3 = 0.f;
        float nb0 = 0.f, nb1 = 0.f, nb2 = 0.f, nb3 = 0.f;
        const float4* kc4 = (const float4*)kc;
        const float4* vc4 = (const float4*)vc;
        for (int j = 0; j < 128; ++j) {
            float4 k4 = kc4[j];
            float4 v4 = vc4[j];
            float ea0 = fast_exp2(fmaf(aa, k4.x, ba));
            float ea1 = fast_exp2(fmaf(aa, k4.y, ba));
            float ea2 = fast_exp2(fmaf(aa, k4.z, ba));
            float ea3 = fast_exp2(fmaf(aa, k4.w, ba));
            float eb0 = fast_exp2(fmaf(ab, k4.x, bb));
            float eb1 = fast_exp2(fmaf(ab, k4.y, bb));
            float eb2 = fast_exp2(fmaf(ab, k4.z, bb));
            float eb3 = fast_exp2(fmaf(ab, k4.w, bb));
            da0 += ea0; na0 = fmaf(ea0, v4.x, na0);
            da1 += ea1; na1 = fmaf(ea1, v4.y, na1);
            da2 += ea2; na2 = fmaf(ea2, v4.z, na2);
            da3 += ea3; na3 = fmaf(ea3, v4.w, na3);
            db0 += eb0; nb0 = fmaf(eb0, v4.x, nb0);
            db1 += eb1; nb1 = fmaf(eb1, v4.y, nb1);
            db2 += eb2; nb2 = fmaf(eb2, v4.z, nb2);
            db3 += eb3; nb3 = fmaf(eb3, v4.w, nb3);
        }
        const float dena = (da0 + da1) + (da2 + da3);
        const float numa = (na0 + na1) + (na2 + na3);
        const float denb = (db0 + db1) + (db2 + db3);
        const float numb = (nb0 + nb1) + (nb2 + nb3);
        const size_t pa = (size_t)jh * 131072 + (size_t)(b * 1024 + qa) * 64 + h;
        const size_t pb = (size_t)jh * 131072 + (size_t)(b * 1024 + qb) * 64 + h;
        numP[pa] = numa; denP[pa] = dena;
        numP[pb] = numb; denP[pb] = denb;

        __syncthreads();                       // no inter-rep LDS race
        asm volatile("" ::: "memory");         // defeat cross-rep CSE
    }
}

// ---------------------------------------------------------------------------
// Stage 3: combine j-half partials, then out = O @ Wo + bo.
// ---------------------------------------------------------------------------
__global__ __launch_bounds__(256) void oproj_kernel(
    const float* __restrict__ numP, const float* __restrict__ denP,
    const float* __restrict__ Wo, const float* __restrict__ bo,
    float* __restrict__ out, int reps)
{
    __shared__ __align__(16) float so[512];   // 8 rows x 64
    const int t  = threadIdx.x;
    const int rb = blockIdx.x;
    const size_t r0 = (size_t)rb * 8;

    for (int rep = 0; rep < reps; ++rep) {
        #pragma unroll
        for (int p = 0; p < 2; ++p) {
            const size_t gi = r0 * 64 + p * 256 + t;
            float n = numP[gi] + numP[gi + 131072];
            float d = denP[gi] + denP[gi + 131072];
            so[p * 256 + t] = n / d;
        }
        __syncthreads();

        const int d2 = t * 2;
        float2 bv = *(const float2*)&bo[d2];
        float acc0[8], acc1[8];
        #pragma unroll
        for (int r = 0; r < 8; ++r) { acc0[r] = bv.x; acc1[r] = bv.y; }
        for (int hh = 0; hh < 64; hh += 4) {
            float2 w0 = *(const float2*)&Wo[(hh + 0) * 512 + d2];
            float2 w1 = *(const float2*)&Wo[(hh + 1) * 512 + d2];
            float2 w2 = *(const float2*)&Wo[(hh + 2) * 512 + d2];
            float2 w3 = *(const float2*)&Wo[(hh + 3) * 512 + d2];
            #pragma unroll
            for (int r = 0; r < 8; ++r) {
                float4 s4 = *(const float4*)&so[r * 64 + hh];
                acc0[r] = fmaf(s4.x, w0.x, acc0[r]); acc1[r] = fmaf(s4.x, w0.y, acc1[r]);
                acc0[r] = fmaf(s4.y, w1.x, acc0[r]); acc1[r] = fmaf(s4.y, w1.y, acc1[r]);
                acc0[r] = fmaf(s4.z, w2.x, acc0[r]); acc1[r] = fmaf(s4.z, w2.y, acc1[r]);
                acc0[r] = fmaf(s4.w, w3.x, acc0[r]); acc1[r] = fmaf(s4.w, w3.y, acc1[r]);
            }
        }
        #pragma unroll
        for (int r = 0; r < 8; ++r)
            *(float2*)&out[(r0 + r) * 512 + d2] = make_float2(acc0[r], acc1[r]);

        __syncthreads();                       // no inter-rep LDS race
        asm volatile("" ::: "memory");         // defeat cross-rep CSE
    }
}

extern "C" void kernel_launch(void* const* d_in, const int* in_sizes, int n_in,
                              void* d_out, int out_size, void* d_ws, size_t ws_size,
                              hipStream_t stream)
{
    const float* x   = (const float*)d_in[0];
    const float* emb = (const float*)d_in[1];
    const float* Wq  = (const float*)d_in[2];
    const float* Wk  = (const float*)d_in[3];
    const float* Wv  = (const float*)d_in[4];
    const float* Wo  = (const float*)d_in[5];
    const float* bo  = (const float*)d_in[6];
    float* out = (float*)d_out;

    // workspace: qT/kT/vT [B,64,1024] + numP/denP [2][B*1024][64] — 3.5 MB
    float* qT   = (float*)d_ws;
    float* kT   = qT + 131072;
    float* vT   = kT + 131072;
    float* numP = vT + 131072;
    float* denP = numP + 262144;

    // MEASUREMENT: reps chosen so each dispatch exceeds the ~40us fill cutoff
    // and appears in rocprof top-5 with its own counters.
    proj_kernel<<<512, 256, 0, stream>>>(x, emb, Wq, Wk, Wv, qT, kT, vT, 8);
    attn_kernel<<<512, 256, 0, stream>>>(qT, kT, vT, numP, denP, 8);
    oproj_kernel<<<256, 256, 0, stream>>>(numP, denP, Wo, bo, out, 24);
}

// Round 8
// 109.426 us; speedup vs baseline: 3.1864x; 3.1864x over previous
//
#include <hip/hip_runtime.h>
#include <hip/hip_bf16.h>

#define LOG2E 1.44269504088896340736f

__device__ __forceinline__ float fast_exp2(float x) {
#if __has_builtin(__builtin_amdgcn_exp2f)
    return __builtin_amdgcn_exp2f(x);
#else
    return exp2f(x);
#endif
}

// packed fp32 pair ops -> v_pk_fma_f32 / v_pk_add_f32 on gfx90a+ (CDNA4).
// Exact fma/add semantics; falls back to scalar (numerically identical).
typedef float f32x2 __attribute__((ext_vector_type(2)));

__device__ __forceinline__ f32x2 pk_fma(f32x2 a, f32x2 b, f32x2 c) {
#if __has_builtin(__builtin_elementwise_fma)
    return __builtin_elementwise_fma(a, b, c);
#else
    f32x2 r; r.x = fmaf(a.x, b.x, c.x); r.y = fmaf(a.y, b.y, c.y); return r;
#endif
}

// ---------------------------------------------------------------------------
// Stage 1: fused QKV projection with transposed outputs (identical to the
// verified version; measured ~6us).
// ---------------------------------------------------------------------------
__global__ __launch_bounds__(256) void proj_kernel(
    const float* __restrict__ x, const float* __restrict__ emb,
    const float* __restrict__ Wq, const float* __restrict__ Wk,
    const float* __restrict__ Wv,
    float* __restrict__ qT, float* __restrict__ kT, float* __restrict__ vT)
{
    __shared__ __align__(16) float sx[4096];    // 8 rows x 512
    __shared__ __align__(16) float sred[4096];  // partial-sum reduction buffer
    const int t   = threadIdx.x;
    const int bid = blockIdx.x;
    const bool isQ = (bid < 256);
    const int rb  = isQ ? bid : (bid - 256);

    const float* src = (isQ ? x : emb) + (size_t)rb * 8 * 512;
    #pragma unroll
    for (int i = 0; i < 16; ++i) sx[i * 256 + t] = src[i * 256 + t];
    __syncthreads();

    const int b  = rb >> 7;          // rows rb*8 -> batch
    const int q0 = (rb << 3) & 1023; // seq offset

    if (isQ) {
        const int cp = (t & 31) * 2;
        const int g  = t >> 5;
        const int d0 = g * 64;
        float acc0[8], acc1[8];
        #pragma unroll
        for (int r = 0; r < 8; ++r) { acc0[r] = 0.f; acc1[r] = 0.f; }
        for (int dd = 0; dd < 64; dd += 4) {
            const int d = d0 + dd;
            float2 w0 = *(const float2*)&Wq[(d + 0) * 64 + cp];
            float2 w1 = *(const float2*)&Wq[(d + 1) * 64 + cp];
            float2 w2 = *(const float2*)&Wq[(d + 2) * 64 + cp];
            float2 w3 = *(const float2*)&Wq[(d + 3) * 64 + cp];
            #pragma unroll
            for (int r = 0; r < 8; ++r) {
                float4 xv = *(const float4*)&sx[r * 512 + d];
                acc0[r] = fmaf(xv.x, w0.x, acc0[r]); acc1[r] = fmaf(xv.x, w0.y, acc1[r]);
                acc0[r] = fmaf(xv.y, w1.x, acc0[r]); acc1[r] = fmaf(xv.y, w1.y, acc1[r]);
                acc0[r] = fmaf(xv.z, w2.x, acc0[r]); acc1[r] = fmaf(xv.z, w2.y, acc1[r]);
                acc0[r] = fmaf(xv.w, w3.x, acc0[r]); acc1[r] = fmaf(xv.w, w3.y, acc1[r]);
            }
        }
        #pragma unroll
        for (int r = 0; r < 8; ++r)
            *(float2*)&sred[g * 512 + r * 64 + cp] = make_float2(acc0[r], acc1[r]);
        __syncthreads();
        #pragma unroll
        for (int p = 0; p < 2; ++p) {
            int idx = p * 256 + t;
            int r = idx >> 6, h = idx & 63;
            float s = 0.f;
            #pragma unroll
            for (int g2 = 0; g2 < 8; ++g2) s += sred[g2 * 512 + r * 64 + h];
            qT[(size_t)(b * 64 + h) * 1024 + q0 + r] = s;
        }
    } else {
        const int cp = (t & 63) * 2;
        const int g  = t >> 6;
        const int d0 = g * 128;
        const float* Wsel = (cp < 64) ? (Wk + cp) : (Wv + (cp - 64));
        float acc0[8], acc1[8];
        #pragma unroll
        for (int r = 0; r < 8; ++r) { acc0[r] = 0.f; acc1[r] = 0.f; }
        for (int dd = 0; dd < 128; dd += 4) {
            const int d = d0 + dd;
            float2 w0 = *(const float2*)&Wsel[(d + 0) * 64];
            float2 w1 = *(const float2*)&Wsel[(d + 1) * 64];
            float2 w2 = *(const float2*)&Wsel[(d + 2) * 64];
            float2 w3 = *(const float2*)&Wsel[(d + 3) * 64];
            #pragma unroll
            for (int r = 0; r < 8; ++r) {
                float4 xv = *(const float4*)&sx[r * 512 + d];
                acc0[r] = fmaf(xv.x, w0.x, acc0[r]); acc1[r] = fmaf(xv.x, w0.y, acc1[r]);
                acc0[r] = fmaf(xv.y, w1.x, acc0[r]); acc1[r] = fmaf(xv.y, w1.y, acc1[r]);
                acc0[r] = fmaf(xv.z, w2.x, acc0[r]); acc1[r] = fmaf(xv.z, w2.y, acc1[r]);
                acc0[r] = fmaf(xv.w, w3.x, acc0[r]); acc1[r] = fmaf(xv.w, w3.y, acc1[r]);
            }
        }
        #pragma unroll
        for (int r = 0; r < 8; ++r)
            *(float2*)&sred[g * 1024 + r * 128 + cp] = make_float2(acc0[r], acc1[r]);
        __syncthreads();
        #pragma unroll
        for (int p = 0; p < 4; ++p) {
            int idx = p * 256 + t;
            int r = idx >> 7, c = idx & 127;
            float s = 0.f;
            #pragma unroll
            for (int g2 = 0; g2 < 4; ++g2) s += sred[g2 * 1024 + r * 128 + c];
            if (c < 64) kT[(size_t)(b * 64 + c) * 1024 + q0 + r] = s;
            else        vT[(size_t)(b * 64 + (c - 64)) * 1024 + q0 + r] = s;
        }
    }
}

// ---------------------------------------------------------------------------
// Stage 2: attention, head_dim==1. Round-7 measurement showed this stage is
// 19.3us/29us window, VALUBusy 76%, LDS conflicts 0, HBM 0.5% -> pure
// VALU/trans ISSUE-bound with ~24% stall (1.4 waves/SIMD avg occupancy).
// Fixes, both aimed at the issue stream:
//  (1) packed fp32 pairs: arg-fma / den-add / num-fma become v_pk_* ops
//      (3 full-rate ops -> 1.5 per element; 14 -> 11 cyc/wave-element).
//      Same fma/add semantics, same accumulator pairing -> bit-identical.
//  (2) grid 512 -> 1024 (b, h, q-quarter, j-half), 4 blocks/CU = 4 waves/SIMD
//      to hide exp latency (qpt back to 1; LDS traffic proven irrelevant in
//      rounds 5/6).
// j-half partials identical to round 6; oproj joins them.
// ---------------------------------------------------------------------------
__global__ __launch_bounds__(256) void attn_kernel(
    const float* __restrict__ qT, const float* __restrict__ kT,
    const float* __restrict__ vT, float* __restrict__ numP,
    float* __restrict__ denP)
{
    __shared__ __align__(16) float kc[512];
    __shared__ __align__(16) float vc[512];
    __shared__ float wred[8];
    const int t   = threadIdx.x;
    const int bid = blockIdx.x;
    const int b   = bid >> 9;          // 512 (h,qq,jh) combos per batch
    const int h   = (bid >> 3) & 63;
    const int qq  = (bid >> 1) & 3;    // q-quarter: rows qq*256 .. +255
    const int jh  = bid & 1;           // j-half: cols jh*512 .. +511
    const size_t base = (size_t)(b * 64 + h) * 1024;

    // full-range k max/min (4 coalesced reads); stage only our j-slice
    float kmx = -1e30f, kmn = 1e30f;
    #pragma unroll
    for (int i = 0; i < 4; ++i) {
        float kv = kT[base + i * 256 + t];
        kmx = fmaxf(kmx, kv);
        kmn = fminf(kmn, kv);
        if ((i >> 1) == jh) kc[(i & 1) * 256 + t] = kv;
    }
    #pragma unroll
    for (int i2 = 0; i2 < 2; ++i2)
        vc[i2 * 256 + t] = vT[base + (jh * 2 + i2) * 256 + t];
    #pragma unroll
    for (int off = 32; off >= 1; off >>= 1) {
        kmx = fmaxf(kmx, __shfl_xor(kmx, off));
        kmn = fminf(kmn, __shfl_xor(kmn, off));
    }
    const int wid = t >> 6;
    if ((t & 63) == 0) { wred[wid] = kmx; wred[4 + wid] = kmn; }
    __syncthreads();
    kmx = fmaxf(fmaxf(wred[0], wred[1]), fmaxf(wred[2], wred[3]));
    kmn = fminf(fminf(wred[4], wred[5]), fminf(wred[6], wred[7]));

    const int q = qq * 256 + t;
    const float qs = qT[base + q];                       // coalesced
    const float m  = (qs >= 0.f) ? qs * kmx : qs * kmn;  // full-range row max
    const float a  = qs * LOG2E;
    const float bb = -m * LOG2E;
    const f32x2 a2 = { a, a };
    const f32x2 b2 = { bb, bb };

    // packed accumulators: (d0,d1),(d2,d3) preserve verified summation order
    f32x2 d01 = { 0.f, 0.f }, d23 = { 0.f, 0.f };
    f32x2 n01 = { 0.f, 0.f }, n23 = { 0.f, 0.f };
    const float4* kc4 = (const float4*)kc;
    const float4* vc4 = (const float4*)vc;
    for (int j = 0; j < 128; ++j) {
        float4 k4 = kc4[j];
        float4 v4 = vc4[j];
        f32x2 k01 = { k4.x, k4.y }, k23 = { k4.z, k4.w };
        f32x2 v01 = { v4.x, v4.y }, v23 = { v4.z, v4.w };
        f32x2 arg01 = pk_fma(a2, k01, b2);
        f32x2 arg23 = pk_fma(a2, k23, b2);
        f32x2 e01, e23;
        e01.x = fast_exp2(arg01.x); e01.y = fast_exp2(arg01.y);
        e23.x = fast_exp2(arg23.x); e23.y = fast_exp2(arg23.y);
        d01 += e01;                   // v_pk_add_f32
        d23 += e23;
        n01 = pk_fma(e01, v01, n01);  // v_pk_fma_f32
        n23 = pk_fma(e23, v23, n23);
    }
    const float den = (d01.x + d01.y) + (d23.x + d23.y);  // (d0+d1)+(d2+d3)
    const float num = (n01.x + n01.y) + (n23.x + n23.y);
    // partial outputs: [jh][b*1024+q][h]
    const size_t p = (size_t)jh * 131072 + (size_t)(b * 1024 + q) * 64 + h;
    numP[p] = num;
    denP[p] = den;
}

// ---------------------------------------------------------------------------
// Stage 3: combine j-half partials, then out = O @ Wo + bo.  [2048x64]@[64x512].
// grid = 256 blocks (8 rows each), 256 threads (2 output cols each).
// ---------------------------------------------------------------------------
__global__ __launch_bounds__(256) void oproj_kernel(
    const float* __restrict__ numP, const float* __restrict__ denP,
    const float* __restrict__ Wo, const float* __restrict__ bo,
    float* __restrict__ out)
{
    __shared__ __align__(16) float so[512];   // 8 rows x 64
    const int t  = threadIdx.x;
    const int rb = blockIdx.x;
    const size_t r0 = (size_t)rb * 8;
    #pragma unroll
    for (int p = 0; p < 2; ++p) {
        const size_t gi = r0 * 64 + p * 256 + t;
        float n = numP[gi] + numP[gi + 131072];
        float d = denP[gi] + denP[gi + 131072];
        so[p * 256 + t] = n / d;
    }
    __syncthreads();

    const int d2 = t * 2;
    float2 bv = *(const float2*)&bo[d2];
    float acc0[8], acc1[8];
    #pragma unroll
    for (int r = 0; r < 8; ++r) { acc0[r] = bv.x; acc1[r] = bv.y; }
    for (int hh = 0; hh < 64; hh += 4) {
        float2 w0 = *(const float2*)&Wo[(hh + 0) * 512 + d2];
        float2 w1 = *(const float2*)&Wo[(hh + 1) * 512 + d2];
        float2 w2 = *(const float2*)&Wo[(hh + 2) * 512 + d2];
        float2 w3 = *(const float2*)&Wo[(hh + 3) * 512 + d2];
        #pragma unroll
        for (int r = 0; r < 8; ++r) {
            float4 s4 = *(const float4*)&so[r * 64 + hh];
            acc0[r] = fmaf(s4.x, w0.x, acc0[r]); acc1[r] = fmaf(s4.x, w0.y, acc1[r]);
            acc0[r] = fmaf(s4.y, w1.x, acc0[r]); acc1[r] = fmaf(s4.y, w1.y, acc1[r]);
            acc0[r] = fmaf(s4.z, w2.x, acc0[r]); acc1[r] = fmaf(s4.z, w2.y, acc1[r]);
            acc0[r] = fmaf(s4.w, w3.x, acc0[r]); acc1[r] = fmaf(s4.w, w3.y, acc1[r]);
        }
    }
    #pragma unroll
    for (int r = 0; r < 8; ++r)
        *(float2*)&out[(r0 + r) * 512 + d2] = make_float2(acc0[r], acc1[r]);
}

extern "C" void kernel_launch(void* const* d_in, const int* in_sizes, int n_in,
                              void* d_out, int out_size, void* d_ws, size_t ws_size,
                              hipStream_t stream)
{
    const float* x   = (const float*)d_in[0];
    const float* emb = (const float*)d_in[1];
    const float* Wq  = (const float*)d_in[2];
    const float* Wk  = (const float*)d_in[3];
    const float* Wv  = (const float*)d_in[4];
    const float* Wo  = (const float*)d_in[5];
    const float* bo  = (const float*)d_in[6];
    float* out = (float*)d_out;

    // workspace: qT/kT/vT [B,64,1024] + numP/denP [2][B*1024][64] — 3.5 MB
    float* qT   = (float*)d_ws;
    float* kT   = qT + 131072;
    float* vT   = kT + 131072;
    float* numP = vT + 131072;
    float* denP = numP + 262144;

    proj_kernel<<<512, 256, 0, stream>>>(x, emb, Wq, Wk, Wv, qT, kT, vT);
    attn_kernel<<<1024, 256, 0, stream>>>(qT, kT, vT, numP, denP);
    oproj_kernel<<<256, 256, 0, stream>>>(numP, denP, Wo, bo, out);
}